// Round 25
// baseline (216.535 us; speedup 1.0000x reference)
//
#include <hip/hip_runtime.h>
#include <cstddef>

#define NPIX 1024   // H*W = 32*32

// ---------------------------------------------------------------------------
// Workspace layouts (float-slot offsets).
// BATCHED (both residual chains as images 0..31): peak 38,174,720 floats.
// FALLBACK (per-chain, R14 layout): peak 34,045,952 floats.
// ---------------------------------------------------------------------------
static constexpr size_t WQKV_OFF  = 0;
static constexpr size_t WPROJ_OFF = 98304;
static constexpr size_t WINV_OFF  = 163840;
static constexpr size_t WPW_OFF   = 294912;
// batched
static constexpr size_t BXT_OFF   = 425984;
static constexpr size_t BQKV_OFF  = 4620288;
static constexpr size_t BDPW_OFF  = 17203200;
static constexpr size_t BATT_OFF  = 29786112;
static constexpr size_t BT1T_OFF  = 425984;     // alias XT32
static constexpr size_t BH1T_OFF  = 4620288;    // alias QKV32..
static constexpr size_t BH2T_OFF  = 21397504;   // alias DPW-tail+ATT
static constexpr size_t BATCH_NEED_F = 38174720;
// fallback (R14)
static constexpr size_t XT_OFF    = 425984;
static constexpr size_t QKV_OFF   = 2523136;
static constexpr size_t DPW_OFF   = 8814592;
static constexpr size_t ATT_OFF   = 15106048;
static constexpr size_t T1_OFF    = 21463040;
static constexpr size_t T1T_OFF   = 25657344;
static constexpr size_t H1T_OFF   = 425984;
static constexpr size_t H2T_OFF   = 25657344;

typedef __attribute__((ext_vector_type(8))) short bf16x8;
typedef __attribute__((ext_vector_type(8))) unsigned short u16x8;
typedef __attribute__((ext_vector_type(4))) unsigned short u16x4;
typedef __attribute__((ext_vector_type(4))) float f32x4;

__device__ inline unsigned short f2bf(float f) {
    union { float f; unsigned int u; } v; v.f = f;
    unsigned int u = v.u;
    u += 0x7FFFu + ((u >> 16) & 1u);        // round-to-nearest-even
    return (unsigned short)(u >> 16);
}
__device__ inline float bf2f(unsigned short u) {
    union { float f; unsigned int u; } v; v.u = ((unsigned int)u) << 16;
    return v.f;
}
__device__ inline u16x8 zero8() {
    u16x8 z = {0, 0, 0, 0, 0, 0, 0, 0};
    return z;
}

// ---------------------------------------------------------------------------
// Weight convert (all 4 weights in ONE launch): fp32 [O][K] -> bf16 [K/8][O][8]
// ---------------------------------------------------------------------------
__global__ __launch_bounds__(256)
void wconv_all(const float* __restrict__ w0, const float* __restrict__ w1,
               const float* __restrict__ w2, const float* __restrict__ w3,
               unsigned short* __restrict__ d0, unsigned short* __restrict__ d1,
               unsigned short* __restrict__ d2, unsigned short* __restrict__ d3)
{
    const int bid = blockIdx.x;
    const float* W; unsigned short* WB; int O, K, base;
    if (bid < 96)       { W = w0; WB = d0; O = 768;  K = 256;  base = 0;   }
    else if (bid < 160) { W = w1; WB = d1; O = 256;  K = 512;  base = 96;  }
    else if (bid < 288) { W = w2; WB = d2; O = 1024; K = 256;  base = 160; }
    else                { W = w3; WB = d3; O = 256;  K = 1024; base = 288; }
    const int idx = (bid - base) * 256 + threadIdx.x;
    if (idx >= O * (K >> 3)) return;
    const int o = idx % O;
    const int koct = idx / O;
    u16x8 v;
#pragma unroll
    for (int j = 0; j < 8; j++) v[j] = f2bf(W[(size_t)o * K + koct * 8 + j]);
    *(u16x8*)(WB + ((size_t)koct * O + o) * 8) = v;
}

// ---------------------------------------------------------------------------
// Transpose, dual-source: image ib<16 from X0, else X1.
// ---------------------------------------------------------------------------
__global__ __launch_bounds__(256)
void xpose2(const float* __restrict__ X0, const float* __restrict__ X1,
            unsigned short* __restrict__ XT, const int C)
{
    __shared__ float tt[8][260];
    const int t = threadIdx.x;
    const int octs = C >> 3;
    const int strips = octs * 4;
    const int ib = blockIdx.x / strips;
    const int rem = blockIdx.x - ib * strips;
    const int coct = rem >> 2;
    const int n0 = (rem & 3) * 256;
    const float* src = (ib < 16) ? X0 + (size_t)ib * C * NPIX
                                 : X1 + (size_t)(ib - 16) * C * NPIX;
    const int cc = t >> 5;
    const int c8 = (t & 31) * 8;
    const float* xp = src + ((size_t)(coct * 8 + cc)) * NPIX + n0 + c8;
    *(float4*)(&tt[cc][c8])     = *(const float4*)(xp);
    *(float4*)(&tt[cc][c8 + 4]) = *(const float4*)(xp + 4);
    __syncthreads();
    u16x8 v;
#pragma unroll
    for (int j = 0; j < 8; j++) v[j] = f2bf(tt[j][t]);
    *(u16x8*)(XT + (((size_t)ib * octs + coct) * NPIX + n0 + t) * 8) = v;
}

// ---------------------------------------------------------------------------
// MFMA GEMM, DIRECT global->VGPR fragments, constexpr-DEPTH register pipeline.
// DEPTH sized to the REGISTER BUDGET (R24 lesson: oversized DEPTH makes the
// compiler collapse the pipeline silently):
//   MI>=4 (128x128 tiles)      -> DEPTH 2  (staging 64 VGPR + acc 64)
//   dual-stream (EPI=3, MI>=2) -> DEPTH 2
//   else                       -> DEPTH 4
// Operands blocked bf16 [K/8][rows][8].  octs/4 must be a multiple of DEPTH.
// EPI: 0 plain; 1 BN + fp32 residual; 2 bias+hswish; 3 DUAL interleaved
//      second K-stream X2 into acc2 (shared A), BN+2*shift+bf16 residuals.
// OMODE: 0 fp32 [c][n] (+ACC); 1 bf16 [c][n] direct; 2 blocked bf16 direct.
// NO epilogue LDS, no barriers.
// ---------------------------------------------------------------------------
template<int BM, int BN, int EPI, bool ACC, int OMODE>
__global__ __launch_bounds__(256)
void gemm_direct(const unsigned short* __restrict__ X, const unsigned short* __restrict__ X2,
                 const unsigned short* __restrict__ W,
                 float* __restrict__ Y, unsigned short* __restrict__ YB,
                 const int O, const int K,
                 const float* __restrict__ res, const float* __restrict__ res2,
                 const unsigned short* __restrict__ resb,
                 const float* __restrict__ bng, const float* __restrict__ bnb,
                 const float* __restrict__ bnm, const float* __restrict__ bnv,
                 const float* __restrict__ bias)
{
    constexpr int TN = NPIX / BN;
    constexpr int WAVES_N = (BN >= 128) ? 2 : 1;
    constexpr int WM = BM / (4 / WAVES_N);
    constexpr int MI = WM / 16;
    constexpr int NJ = 4;
    constexpr int DEPTH = (MI >= 4) ? 2 : ((EPI == 3 && MI >= 2) ? 2 : 4);

    const int t    = threadIdx.x;
    const int lane = t & 63;
    const int w    = t >> 6;

    // XCD-bijective block swizzle (all grids are multiples of 8)
    const int gx  = gridDim.x;
    const int nwg = gx * gridDim.y;
    int bid = blockIdx.y * gx + blockIdx.x;
    bid = (bid & 7) * (nwg >> 3) + (bid >> 3);
    const int bx = bid % gx;
    const int by = bid / gx;

    const int o0 = bx * BM;
    const int b  = by / TN;
    const int n0 = (by % TN) * BN;

    const int wn = (WAVES_N == 2) ? (w & 1) * 64 : 0;
    const int wo = (WAVES_N == 2) ? (w >> 1) * WM : w * WM;

    const int l16 = lane & 15;
    const int lq  = lane >> 4;

    f32x4 acc[MI][NJ];
    f32x4 acc2[MI][NJ];
#pragma unroll
    for (int i = 0; i < MI; i++)
#pragma unroll
        for (int j = 0; j < NJ; j++) {
            f32x4 z = {0.f, 0.f, 0.f, 0.f};
            acc[i][j] = z;
            acc2[i][j] = z;
        }

    const unsigned short* Ab = W + ((size_t)lq * O + o0 + wo + l16) * 8;
    const size_t strideA = (size_t)O * 8;
    const size_t strideB = (size_t)NPIX * 8;
    const size_t boff = ((size_t)lq * NPIX + n0 + wn + l16) * 8;
    const int octs = K >> 3;                    // multiple of 4*DEPTH

    auto ldA_ = [&](bf16x8* fr, int kb) {
#pragma unroll
        for (int i = 0; i < MI; i++)
            fr[i] = *(const bf16x8*)(Ab + (size_t)kb * strideA + i * 128);
    };
    auto ldB_ = [&](bf16x8* fr, const unsigned short* Bb, int kb) {
#pragma unroll
        for (int j = 0; j < NJ; j++)
            fr[j] = *(const bf16x8*)(Bb + (size_t)kb * strideB + j * 128);
    };
    auto domfma_ = [&](f32x4 (&ac)[MI][NJ], bf16x8* af, bf16x8* bf) {
#pragma unroll
        for (int i = 0; i < MI; i++)
#pragma unroll
            for (int j = 0; j < NJ; j++)
                ac[i][j] = __builtin_amdgcn_mfma_f32_16x16x32_bf16(
                    af[i], bf[j], ac[i][j], 0, 0, 0);
    };

    {
        const unsigned short* B1 = X + (size_t)b * K * NPIX + boff;
        const unsigned short* B2 = (EPI == 3)
            ? X2 + (size_t)b * K * NPIX + boff : nullptr;
        bf16x8 aS[DEPTH][MI], bS[DEPTH][NJ], qS[DEPTH][NJ];
#pragma unroll
        for (int d = 0; d < DEPTH; d++) {
            ldA_(aS[d], d * 4);
            ldB_(bS[d], B1, d * 4);
            if (EPI == 3) ldB_(qS[d], B2, d * 4);
        }
        for (int kb = 0; kb < octs; kb += 4 * DEPTH) {
#pragma unroll
            for (int d = 0; d < DEPTH; d++) {
                domfma_(acc, aS[d], bS[d]);
                if (EPI == 3) domfma_(acc2, aS[d], qS[d]);
                const int nxt = kb + (DEPTH + d) * 4;
                if (nxt < octs) {
                    ldA_(aS[d], nxt);
                    ldB_(bS[d], B1, nxt);
                    if (EPI == 3) ldB_(qS[d], B2, nxt);
                }
            }
        }
    }

    // epilogue. C/D: col = lane&15 (n), row = (lane>>4)*4 + reg (o)
    const int r0q = lq * 4;
    float scale[MI][4], shift[MI][4];
    if (EPI == 1 || EPI == 3) {
#pragma unroll
        for (int i = 0; i < MI; i++)
#pragma unroll
            for (int r = 0; r < 4; r++) {
                const int o = o0 + wo + i * 16 + r0q + r;
                const float inv = bng[o] / sqrtf(bnv[o] + 1e-5f);
                scale[i][r] = inv;
                shift[i][r] = bnb[o] - bnm[o] * inv;
            }
    } else if (EPI == 2) {
#pragma unroll
        for (int i = 0; i < MI; i++)
#pragma unroll
            for (int r = 0; r < 4; r++)
                shift[i][r] = bias[o0 + wo + i * 16 + r0q + r];
    }

#pragma unroll
    for (int i = 0; i < MI; i++) {
#pragma unroll
        for (int j = 0; j < NJ; j++) {
            const int nn = n0 + wn + j * 16 + l16;
            const int ob = wo + i * 16 + r0q;           // o base within tile
            const size_t base = ((size_t)b * O + o0 + ob) * NPIX + nn;
            u16x4 r1v, r2v;
            if (EPI == 3) {
                const size_t ro = (((size_t)(b * 32 + ((o0 + ob) >> 3)) * NPIX + nn) * 8
                                   + ((o0 + ob) & 7));
                r1v = *(const u16x4*)(resb + ro);
                r2v = *(const u16x4*)(resb + (size_t)16 * 262144 + ro);
            }
            u16x4 p4;
#pragma unroll
            for (int r = 0; r < 4; r++) {
                const size_t off = base + (size_t)r * NPIX;
                float v = acc[i][j][r];
                if (EPI == 1) {
                    const float* rs = (b < 16) ? res : res2;
                    const size_t roff = ((size_t)(b & 15) * O + o0 + ob + r) * NPIX + nn;
                    v = v * scale[i][r] + shift[i][r] + rs[roff];
                } else if (EPI == 2) {
                    v += shift[i][r];
                    v = v * fminf(fmaxf(v + 3.f, 0.f), 6.f) * (1.f / 6.f);
                } else if (EPI == 3) {
                    v = (v + acc2[i][j][r]) * scale[i][r] + 2.f * shift[i][r]
                        + bf2f(r1v[r]) + bf2f(r2v[r]);
                }
                if (OMODE == 0 || OMODE == 3) {
                    if (ACC) v += Y[off];
                    Y[off] = v;
                }
                if (OMODE == 1) {
                    YB[off] = f2bf(v);                 // direct [c][n] store
                } else if (OMODE >= 2) {
                    p4[r] = f2bf(v);
                }
            }
            if (OMODE >= 2) {
                // direct blocked store: lane's 4 regs = 4 contiguous channels
                const int oct = (o0 + ob) >> 3;
                const int sub = (o0 + ob) & 7;         // 0 or 4
                *(u16x4*)(YB + (((size_t)b * (O >> 3) + oct) * NPIX + nn) * 8 + sub) = p4;
            }
        }
    }
}

// ---------------------------------------------------------------------------
// Depthwise 5x5 SAME, bf16 [c][n] in/out. 2 channels/block, stride-44 fp32 LDS.
// ---------------------------------------------------------------------------
__global__ __launch_bounds__(256)
void dwconv5x5_v3(const unsigned short* __restrict__ X, const float* __restrict__ Wd,
                  unsigned short* __restrict__ Y)
{
    __shared__ float tile[2 * 36 * 44];
    __shared__ float wl[64];
    const int t     = threadIdx.x;
    const int cpair = blockIdx.x % 384;
    const int b     = blockIdx.x / 384;
    const int cbase = cpair * 2;
    const unsigned short* xp = X + ((size_t)b * 768 + cbase) * NPIX;

#pragma unroll
    for (int k = 0; k < 4; k++) {
        const int i = t + k * 256;
        if (i < 792) {
            f32x4 z = {0.f, 0.f, 0.f, 0.f};
            *(f32x4*)(&tile[i * 4]) = z;
        }
    }
    if (t < 50) wl[(t / 25) * 32 + (t % 25)] = Wd[cbase * 25 + t];
    __syncthreads();

    const int ch = t >> 7;
    const int tm = t & 127;
    const int r  = tm >> 2;
    const int c8 = (tm & 3) * 8;

    {
        const u16x8 v = *(const u16x8*)(xp + (size_t)ch * NPIX + r * 32 + c8);
        float* wp = &tile[ch * 1584 + (r + 2) * 44 + c8 + 2];
#pragma unroll
        for (int j = 0; j < 8; j += 2) {
            float2 f2v = make_float2(bf2f(v[j]), bf2f(v[j + 1]));
            *(float2*)(wp + j) = f2v;
        }
    }
    float wk[25];
#pragma unroll
    for (int i = 0; i < 25; i++) wk[i] = wl[ch * 32 + i];
    __syncthreads();

    float acc[8];
#pragma unroll
    for (int j = 0; j < 8; j++) acc[j] = 0.f;

#pragma unroll
    for (int ky = 0; ky < 5; ky++) {
        const float* rp = &tile[ch * 1584 + (r + ky) * 44 + c8];
        const f32x4 a = *(const f32x4*)(rp);
        const f32x4 bq = *(const f32x4*)(rp + 4);
        const f32x4 cq = *(const f32x4*)(rp + 8);
        const float in[12] = {a[0], a[1], a[2], a[3], bq[0], bq[1], bq[2], bq[3],
                              cq[0], cq[1], cq[2], cq[3]};
#pragma unroll
        for (int kx = 0; kx < 5; kx++) {
            const float wv = wk[ky * 5 + kx];
#pragma unroll
            for (int j = 0; j < 8; j++)
                acc[j] = fmaf(in[j + kx], wv, acc[j]);
        }
    }

    u16x8 o8;
#pragma unroll
    for (int j = 0; j < 8; j++) o8[j] = f2bf(acc[j]);
    *(u16x8*)(Y + ((size_t)b * 768 + cbase + ch) * NPIX + r * 32 + c8) = o8;
}

// ---------------------------------------------------------------------------
// Depthwise 3x3 + bias + hswish, blocked bf16 in/out — 2 px x 8 ch per thread,
// direct global reads, no pixel LDS.
// ---------------------------------------------------------------------------
__global__ __launch_bounds__(256)
void dwconv3x3_h2(const unsigned short* __restrict__ X, const float* __restrict__ Wd,
                  const float* __restrict__ bias, unsigned short* __restrict__ Y)
{
    __shared__ float wl[72];
    __shared__ float bb[8];
    const int t    = threadIdx.x;
    const int bid  = blockIdx.x;
    const int half = bid & 1;
    const int coct = (bid >> 1) & 127;
    const int b    = bid >> 8;
    const unsigned short* xp = X + ((size_t)(b * 128 + coct)) * NPIX * 8;
    if (t < 72) wl[t] = Wd[coct * 72 + t];
    if (t < 8)  bb[t] = bias[coct * 8 + t];
    __syncthreads();

    const int px0 = half * 512 + t * 2;   // 2 consecutive pixels
    const int hr  = px0 >> 5;             // image row
    const int c0  = px0 & 31;             // image col (even)

    float acc[8][2];
#pragma unroll
    for (int ch = 0; ch < 8; ch++) {
        acc[ch][0] = bb[ch];
        acc[ch][1] = bb[ch];
    }

#pragma unroll
    for (int ky = 0; ky < 3; ky++) {
        const int rr = hr + ky - 1;
        if (rr >= 0 && rr < 32) {
            u16x8 P[4];
#pragma unroll
            for (int m = 0; m < 4; m++) {
                const int col = c0 - 1 + m;
                const int colc = col < 0 ? 0 : (col > 31 ? 31 : col);
                u16x8 v = *(const u16x8*)(xp + (size_t)(rr * 32 + colc) * 8);
                if (col < 0 || col > 31) v = zero8();
                P[m] = v;
            }
#pragma unroll
            for (int ch = 0; ch < 8; ch++) {
                float g[4];
#pragma unroll
                for (int m = 0; m < 4; m++) g[m] = bf2f(P[m][ch]);
#pragma unroll
                for (int j = 0; j < 2; j++)
#pragma unroll
                    for (int kx = 0; kx < 3; kx++)
                        acc[ch][j] = fmaf(g[j + kx], wl[ch * 9 + ky * 3 + kx], acc[ch][j]);
            }
        }
    }
    unsigned short* yp = Y + ((size_t)(b * 128 + coct)) * NPIX * 8 + (size_t)px0 * 8;
#pragma unroll
    for (int j = 0; j < 2; j++) {
        u16x8 o8;
#pragma unroll
        for (int ch = 0; ch < 8; ch++) {
            float v = acc[ch][j];
            v = v * fminf(fmaxf(v + 3.f, 0.f), 6.f) * (1.f / 6.f);
            o8[ch] = f2bf(v);
        }
        *(u16x8*)(yp + j * 8) = o8;
    }
}

// ---------------------------------------------------------------------------
// Grouped 32->32 1x1 via MFMA: one block per (b,g), 4 waves x 256-px chunks.
// ---------------------------------------------------------------------------
__global__ __launch_bounds__(256)
void grouped_mfma(unsigned short* __restrict__ D, const float* __restrict__ Wg)
{
    const int t    = threadIdx.x;
    const int lane = t & 63;
    const int w    = t >> 6;
    const int bg   = blockIdx.x;          // b*24 + g
    const int g    = bg % 24;
    const int b    = bg / 24;
    const int l16  = lane & 15;
    const int lq   = lane >> 4;
    const int ko   = lq * 8;              // i-oct within K=32
    const int nb   = w * 256;

    unsigned short* dp = D + ((size_t)(b * 768 + g * 32)) * NPIX;

    // A-frags from fp32 weights: a0 -> o = l16, a1 -> o = 16+l16 (i contiguous)
    bf16x8 a0, a1;
#pragma unroll
    for (int j = 0; j < 8; j++) {
        a0[j] = (short)f2bf(Wg[g * 1024 + l16 * 32 + ko + j]);
        a1[j] = (short)f2bf(Wg[g * 1024 + (16 + l16) * 32 + ko + j]);
    }

    // B-frags: 16 n-tiles of 16 px; lane (lq,l16): b[j] = in[ko+j][nb+tl*16+l16]
    bf16x8 bfr[16];
    const unsigned short* ib = dp + (size_t)ko * NPIX + nb + l16;
#pragma unroll
    for (int tl = 0; tl < 16; tl++) {
        bf16x8 bf;
#pragma unroll
        for (int j = 0; j < 8; j++)
            bf[j] = (short)ib[(size_t)j * NPIX + tl * 16];
        bfr[tl] = bf;
    }

    // compute + store (all reads above complete before any write)
    const int ro = lq * 4;
#pragma unroll
    for (int tl = 0; tl < 16; tl++) {
        f32x4 c0 = {0.f, 0.f, 0.f, 0.f};
        f32x4 c1 = {0.f, 0.f, 0.f, 0.f};
        c0 = __builtin_amdgcn_mfma_f32_16x16x32_bf16(a0, bfr[tl], c0, 0, 0, 0);
        c1 = __builtin_amdgcn_mfma_f32_16x16x32_bf16(a1, bfr[tl], c1, 0, 0, 0);
        const int n = nb + tl * 16 + l16;
#pragma unroll
        for (int r = 0; r < 4; r++) {
            dp[(size_t)(ro + r) * NPIX + n]        = f2bf(c0[r]);
            dp[(size_t)(16 + ro + r) * NPIX + n]   = f2bf(c1[r]);
        }
    }
}

// ---------------------------------------------------------------------------
// FUSED attention v3: one block per (b,h), 8 WAVES (512 threads).
// ---------------------------------------------------------------------------
__global__ __launch_bounds__(512)
void attn_fused(const unsigned short* __restrict__ qkv,
                const unsigned short* __restrict__ dpw,
                unsigned short* __restrict__ att)
{
    __shared__ float kvred[8][33 * 33];
    __shared__ float kvs[1056];

    const int t    = threadIdx.x;
    const int lane = t & 63;
    const int w    = t >> 6;              // 0..7
    const int bh   = blockIdx.x;
    const int b    = bh >> 4;
    const int h    = bh & 15;

    const unsigned short* base = (h < 8)
        ? qkv + ((size_t)(b * 768 + h * 96)) * NPIX
        : dpw + ((size_t)(b * 768 + (h - 8) * 96)) * NPIX;
    const unsigned short* qp = base;
    const unsigned short* kp = base + 32 * NPIX;
    const unsigned short* vp = base + 64 * NPIX;

    const int l16 = lane & 15;
    const int lq  = lane >> 4;
    const int ko  = lq * 8;
    const int nb  = w * 128;              // 128-px chunk per wave

    // phase 1: kv partials over this wave's 128 px (4 k-steps of 32)
    {
        f32x4 acc[3][2];
#pragma unroll
        for (int i = 0; i < 3; i++)
#pragma unroll
            for (int j = 0; j < 2; j++) {
                f32x4 z = {0.f, 0.f, 0.f, 0.f};
                acc[i][j] = z;
            }
        bf16x8 ones;
#pragma unroll
        for (int j = 0; j < 8; j++) ones[j] = (l16 == 0) ? (short)0x3F80 : (short)0;

#pragma unroll
        for (int s = 0; s < 4; s++) {
            const int n0 = nb + s * 32 + ko;
            const bf16x8 av0 = *(const bf16x8*)(vp + (size_t)l16 * NPIX + n0);
            const bf16x8 av1 = *(const bf16x8*)(vp + (size_t)(16 + l16) * NPIX + n0);
            const u16x8 k0 = *(const u16x8*)(kp + (size_t)l16 * NPIX + n0);
            const u16x8 k1 = *(const u16x8*)(kp + (size_t)(16 + l16) * NPIX + n0);
            bf16x8 bk0, bk1;
#pragma unroll
            for (int j = 0; j < 8; j++) {
                bk0[j] = (k0[j] & 0x8000u) ? (short)0 : (short)k0[j];
                bk1[j] = (k1[j] & 0x8000u) ? (short)0 : (short)k1[j];
            }
            acc[0][0] = __builtin_amdgcn_mfma_f32_16x16x32_bf16(av0,  bk0, acc[0][0], 0, 0, 0);
            acc[0][1] = __builtin_amdgcn_mfma_f32_16x16x32_bf16(av0,  bk1, acc[0][1], 0, 0, 0);
            acc[1][0] = __builtin_amdgcn_mfma_f32_16x16x32_bf16(av1,  bk0, acc[1][0], 0, 0, 0);
            acc[1][1] = __builtin_amdgcn_mfma_f32_16x16x32_bf16(av1,  bk1, acc[1][1], 0, 0, 0);
            acc[2][0] = __builtin_amdgcn_mfma_f32_16x16x32_bf16(ones, bk0, acc[2][0], 0, 0, 0);
            acc[2][1] = __builtin_amdgcn_mfma_f32_16x16x32_bf16(ones, bk1, acc[2][1], 0, 0, 0);
        }
        const int rbase = lq * 4;
#pragma unroll
        for (int dt = 0; dt < 2; dt++)
#pragma unroll
            for (int et = 0; et < 2; et++)
#pragma unroll
                for (int r = 0; r < 4; r++)
                    kvred[w][(dt * 16 + rbase + r) * 33 + et * 16 + l16] = acc[dt][et][r];
        if (rbase == 0) {
#pragma unroll
            for (int et = 0; et < 2; et++)
                kvred[w][32 * 33 + et * 16 + l16] = acc[2][et][0];
        }
    }
    __syncthreads();
#pragma unroll
    for (int k = 0; k < 3; k++) {
        const int idx = t + k * 512;
        if (idx < 1056) {
            const int a = (idx >> 5) * 33 + (idx & 31);
            float s = 0.f;
#pragma unroll
            for (int ww = 0; ww < 8; ww++) s += kvred[ww][a];
            kvs[idx] = s;
        }
    }
    __syncthreads();

    // phase 2: out = kv · relu(Q), K=32; this wave covers 8 n-tiles of 16 px.
    bf16x8 a0, a1, a2;
#pragma unroll
    for (int j = 0; j < 8; j++) {
        a0[j] = (short)f2bf(kvs[l16 * 32 + ko + j]);
        a1[j] = (short)f2bf(kvs[(16 + l16) * 32 + ko + j]);
        a2[j] = (l16 == 0) ? (short)f2bf(kvs[32 * 32 + ko + j]) : (short)0;
    }
    bf16x8 bfr[8];
    const unsigned short* qb = qp + (size_t)ko * NPIX + nb + l16;
#pragma unroll
    for (int tl = 0; tl < 8; tl++) {
        bf16x8 bf;
#pragma unroll
        for (int j = 0; j < 8; j++) {
            const unsigned short v = qb[(size_t)j * NPIX + tl * 16];
            bf[j] = (v & 0x8000u) ? (short)0 : (short)v;
        }
        bfr[tl] = bf;
    }

    const int db0 = lq >> 1;
    const int sub = (lq & 1) * 4;
    unsigned short* ab0 = att + (((size_t)(b * 64 + h * 4 + db0)) * NPIX) * 8 + sub;
    unsigned short* ab1 = att + (((size_t)(b * 64 + h * 4 + 2 + db0)) * NPIX) * 8 + sub;

#pragma unroll
    for (int tl = 0; tl < 8; tl++) {
        f32x4 z = {0.f, 0.f, 0.f, 0.f};
        z = __builtin_amdgcn_mfma_f32_16x16x32_bf16(a2, bfr[tl], z, 0, 0, 0);
        const float den = __shfl(z[0], l16, 64);     // den(col l16) from lane l16
        const float inv = 1.f / (den + 1e-15f);
        f32x4 c0 = {0.f, 0.f, 0.f, 0.f};
        f32x4 c1 = {0.f, 0.f, 0.f, 0.f};
        c0 = __builtin_amdgcn_mfma_f32_16x16x32_bf16(a0, bfr[tl], c0, 0, 0, 0);
        c1 = __builtin_amdgcn_mfma_f32_16x16x32_bf16(a1, bfr[tl], c1, 0, 0, 0);
        u16x4 p0, p1;
#pragma unroll
        for (int r = 0; r < 4; r++) {
            p0[r] = f2bf(c0[r] * inv);
            p1[r] = f2bf(c1[r] * inv);
        }
        const size_t n8 = (size_t)(nb + tl * 16 + l16) * 8;
        *(u16x4*)(ab0 + n8) = p0;
        *(u16x4*)(ab1 + n8) = p1;
    }
}

// ---------------------------------------------------------------------------
extern "C" void kernel_launch(void* const* d_in, const int* in_sizes, int n_in,
                              void* d_out, int out_size, void* d_ws, size_t ws_size,
                              hipStream_t stream)
{
    (void)in_sizes; (void)n_in; (void)out_size;

    const float* x      = (const float*)d_in[0];
    const float* y      = (const float*)d_in[1];
    const float* qkv_w  = (const float*)d_in[2];
    const float* dw5_w  = (const float*)d_in[3];
    const float* pwg_w  = (const float*)d_in[4];
    const float* proj_w = (const float*)d_in[5];
    const float* proj_g = (const float*)d_in[6];
    const float* proj_b = (const float*)d_in[7];
    const float* proj_m = (const float*)d_in[8];
    const float* proj_v = (const float*)d_in[9];
    const float* inv_w  = (const float*)d_in[10];
    const float* inv_b  = (const float*)d_in[11];
    const float* dwc_w  = (const float*)d_in[12];
    const float* dwc_b  = (const float*)d_in[13];
    const float* pw_w   = (const float*)d_in[14];
    const float* pw_g   = (const float*)d_in[15];
    const float* pw_b   = (const float*)d_in[16];
    const float* pw_m   = (const float*)d_in[17];
    const float* pw_v   = (const float*)d_in[18];

    float* ws = (float*)d_ws;
    unsigned short* wqkv_b  = (unsigned short*)(ws + WQKV_OFF);
    unsigned short* wproj_b = (unsigned short*)(ws + WPROJ_OFF);
    unsigned short* winv_b  = (unsigned short*)(ws + WINV_OFF);
    unsigned short* wpw_b   = (unsigned short*)(ws + WPW_OFF);
    float* out = (float*)d_out;

    wconv_all<<<dim3(416), 256, 0, stream>>>(qkv_w, proj_w, inv_w, pw_w,
                                             wqkv_b, wproj_b, winv_b, wpw_b);

    if (ws_size >= (size_t)BATCH_NEED_F * 4ull) {
        // ---------------- batched path: both chains as images 0..31 ----------
        unsigned short* bxt  = (unsigned short*)(ws + BXT_OFF);
        unsigned short* bqkv = (unsigned short*)(ws + BQKV_OFF);
        unsigned short* bdpw = (unsigned short*)(ws + BDPW_OFF);
        unsigned short* batt = (unsigned short*)(ws + BATT_OFF);
        unsigned short* bt1t = (unsigned short*)(ws + BT1T_OFF);
        unsigned short* bh1t = (unsigned short*)(ws + BH1T_OFF);
        unsigned short* bh2t = (unsigned short*)(ws + BH2T_OFF);

        xpose2<<<dim3(4096), 256, 0, stream>>>(x, y, bxt, 256);
        gemm_direct<128, 128, 0, false, 1><<<dim3(6, 256), 256, 0, stream>>>(
            bxt, nullptr, wqkv_b, nullptr, bqkv, 768, 256,
            nullptr, nullptr, nullptr, nullptr, nullptr, nullptr, nullptr, nullptr);
        dwconv5x5_v3<<<dim3(12288), 256, 0, stream>>>(bqkv, dw5_w, bdpw);
        grouped_mfma<<<dim3(768), 256, 0, stream>>>(bdpw, pwg_w);
        attn_fused<<<dim3(512), 512, 0, stream>>>(bqkv, bdpw, batt);
        gemm_direct<64, 64, 1, false, 2><<<dim3(4, 512), 256, 0, stream>>>(
            batt, nullptr, wproj_b, nullptr, bt1t, 256, 512,
            x, y, nullptr, proj_g, proj_b, proj_m, proj_v, nullptr);
        gemm_direct<128, 128, 2, false, 2><<<dim3(8, 256), 256, 0, stream>>>(
            bt1t, nullptr, winv_b, nullptr, bh1t, 1024, 256,
            nullptr, nullptr, nullptr, nullptr, nullptr, nullptr, nullptr, inv_b);
        dwconv3x3_h2<<<dim3(8192), 256, 0, stream>>>(bh1t, dwc_w, dwc_b, bh2t);
        gemm_direct<64, 128, 3, false, 0><<<dim3(4, 128), 256, 0, stream>>>(
            bh2t, bh2t + (size_t)16 * 1024 * 1024, wpw_b, out, nullptr, 256, 1024,
            nullptr, nullptr, bt1t, pw_g, pw_b, pw_m, pw_v, nullptr);
    } else {
        // ---------------- fallback: per-chain (R14 structure) ----------------
        unsigned short* wxt  = (unsigned short*)(ws + XT_OFF);
        unsigned short* wqkv = (unsigned short*)(ws + QKV_OFF);
        unsigned short* wdpw = (unsigned short*)(ws + DPW_OFF);
        unsigned short* watt = (unsigned short*)(ws + ATT_OFF);
        float*          wt1  = ws + T1_OFF;
        unsigned short* wt1t = (unsigned short*)(ws + T1T_OFF);
        unsigned short* wh1t = (unsigned short*)(ws + H1T_OFF);
        unsigned short* wh2t = (unsigned short*)(ws + H2T_OFF);

        for (int blk = 0; blk < 2; blk++) {
            const float* t = (blk == 0) ? x : y;
            xpose2<<<dim3(2048), 256, 0, stream>>>(t, t, wxt, 256);
            gemm_direct<128, 128, 0, false, 1><<<dim3(6, 128), 256, 0, stream>>>(
                wxt, nullptr, wqkv_b, nullptr, wqkv, 768, 256,
                nullptr, nullptr, nullptr, nullptr, nullptr, nullptr, nullptr, nullptr);
            dwconv5x5_v3<<<dim3(6144), 256, 0, stream>>>(wqkv, dw5_w, wdpw);
            grouped_mfma<<<dim3(384), 256, 0, stream>>>(wdpw, pwg_w);
            attn_fused<<<dim3(256), 512, 0, stream>>>(wqkv, wdpw, watt);
            gemm_direct<64, 64, 1, false, 3><<<dim3(4, 256), 256, 0, stream>>>(
                watt, watt, wproj_b, wt1, wt1t, 256, 512,
                t, t, nullptr, proj_g, proj_b, proj_m, proj_v, nullptr);
            gemm_direct<128, 128, 2, false, 2><<<dim3(8, 128), 256, 0, stream>>>(
                wt1t, nullptr, winv_b, nullptr, wh1t, 1024, 256,
                nullptr, nullptr, nullptr, nullptr, nullptr, nullptr, nullptr, inv_b);
            dwconv3x3_h2<<<dim3(4096), 256, 0, stream>>>(wh1t, dwc_w, dwc_b, wh2t);
            if (blk == 0) {
                gemm_direct<64, 64, 1, false, 0><<<dim3(4, 256), 256, 0, stream>>>(
                    wh2t, nullptr, wpw_b, out, nullptr, 256, 1024,
                    wt1, wt1, nullptr, pw_g, pw_b, pw_m, pw_v, nullptr);
            } else {
                gemm_direct<64, 64, 1, true, 0><<<dim3(4, 256), 256, 0, stream>>>(
                    wh2t, nullptr, wpw_b, out, nullptr, 256, 1024,
                    wt1, wt1, nullptr, pw_g, pw_b, pw_m, pw_v, nullptr);
            }
        }
    }
}